// Round 1
// baseline (2792.463 us; speedup 1.0000x reference)
//
#include <hip/hip_runtime.h>
#include <utility>

// Problem constants (from reference)
#define NB   32
#define CH   2
#define HH   640
#define WW   640
#define HW   (HH * WW)        // 409600 pixels per image
#define NHW  (NB * HW)        // 13107200 pixels total
#define PLANE (CH * HW)       // 819200 floats per image, planar
#define HALF (NB * PLANE)     // 26214400 floats per output tensor

#define BLK_PX       512                   // pixels per block (256 thr x 2 px)
#define BLKS_PER_IMG (HW / BLK_PX)         // 800
#define GRID_STEP    (NB * BLKS_PER_IMG)   // 25600

// --- non-temporal load/store helpers (clang builtins need vector types) ---
typedef float v4f __attribute__((ext_vector_type(4)));
typedef float v2f __attribute__((ext_vector_type(2)));

__device__ __forceinline__ float4 nt_load4(const float4* p) {
    v4f t = __builtin_nontemporal_load((const v4f*)p);
    return make_float4(t.x, t.y, t.z, t.w);
}
__device__ __forceinline__ void nt_store4(float4 v, float4* p) {
    v4f t; t.x = v.x; t.y = v.y; t.z = v.z; t.w = v.w;
    __builtin_nontemporal_store(t, (v4f*)p);
}
__device__ __forceinline__ void nt_store2(float2 v, float2* p) {
    v2f t; t.x = v.x; t.y = v.y;
    __builtin_nontemporal_store(t, (v2f*)p);
}

// K0: v [N,2,H,W] planar -> disp0 interleaved [N,H,W,2], scaled by 2^-32
__global__ void k_init(const float* __restrict__ v, float2* __restrict__ out) {
    int idx = blockIdx.x * blockDim.x + threadIdx.x;
    if (idx >= NHW) return;
    int n = idx / HW;
    int p = idx - n * HW;
    const float s = 2.3283064365386963e-10f;  // 2^-32, exact
    float dx = v[n * PLANE + p] * s;
    float dy = v[n * PLANE + HW + p] * s;
    nt_store2(make_float2(dx, dy), &out[idx]);
}

// Bilinear sample with border clamp, align_corners=True. img interleaved [H,W,2].
__device__ __forceinline__ float2 bilin_sample(const float2* __restrict__ img,
                                               float gx, float gy) {
    float fx = (gx + 1.0f) * (0.5f * (float)(WW - 1));
    float fy = (gy + 1.0f) * (0.5f * (float)(HH - 1));
    fx = fminf(fmaxf(fx, 0.0f), (float)(WW - 1));
    fy = fminf(fmaxf(fy, 0.0f), (float)(HH - 1));
    float x0f = floorf(fx);
    float y0f = floorf(fy);
    int x0 = (int)x0f;
    int y0 = (int)y0f;
    int x1 = min(x0 + 1, WW - 1);
    int y1 = min(y0 + 1, HH - 1);
    float wx = fx - x0f;
    float wy = fy - y0f;
    float omwx = 1.0f - wx;
    float omwy = 1.0f - wy;
    float2 v00 = img[y0 * WW + x0];
    float2 v01 = img[y0 * WW + x1];
    float2 v10 = img[y1 * WW + x0];
    float2 v11 = img[y1 * WW + x1];
    float topx = v00.x * omwx + v01.x * wx;
    float topy = v00.y * omwx + v01.y * wx;
    float botx = v10.x * omwx + v11.x * wx;
    float boty = v10.y * omwx + v11.y * wx;
    return make_float2(topx * omwy + botx * wy, topy * omwy + boty * wy);
}

// Block -> (image, pixel-quad) with image pinned to XCD (blockIdx%8 heuristic).
__device__ __forceinline__ void decode_block(int b, int& n, int& q) {
    int xcd = b & 7;
    int slot = b >> 3;                   // 0..3199
    int img_round = slot / BLKS_PER_IMG; // 0..3
    int blk = slot - img_round * BLKS_PER_IMG;
    n = img_round * 8 + xcd;             // image -> fixed XCD
    q = blk * (BLK_PX / 2) + threadIdx.x;   // float4 (pixel-pair) index in image
}

// One squaring step, 2 px/thread. Cache policy: keep the gather image (in)
// L2-resident; stream ig (nt load) and out (nt store) past L2 so the 3.28 MB
// image fits the 4 MB per-XCD L2 and late-step scattered gathers hit L2.
// STEP is only a symbol tag so rocprof separates the 32 dispatches.
template<int STEP>
__global__ __launch_bounds__(256) void k_step(const float2* __restrict__ in,
                                              const float2* __restrict__ ig,
                                              float2* __restrict__ out) {
    int n, q;
    decode_block(blockIdx.x, n, q);

    const float2* img  = in + (size_t)n * HW;
    const float4* img4 = (const float4*)img;
    const float4* ig4  = (const float4*)ig;
    float4 d = img4[q];            // cached: warms L2 for this image's gathers
    float4 g = nt_load4(&ig4[q]);  // streamed: no L2 pollution

    float2 s0 = bilin_sample(img, g.x + d.x, g.y + d.y);
    float2 s1 = bilin_sample(img, g.z + d.z, g.w + d.w);

    float4 o = make_float4(d.x + s0.x, d.y + s0.y, d.z + s1.x, d.w + s1.y);
    float4* out4 = (float4*)(out + (size_t)n * HW);
    nt_store4(o, &out4[q]);        // streamed: only the NEXT dispatch reads it
}

// Final squaring step fused with the epilogue: reads disp31 (interleaved, in ws),
// writes BOTH planar outputs: disp32 -> disp, ig+disp32 -> trans.
// Replaces k_step<32> + k_deinterleave + k_trans (630 MB) with 315 MB.
__global__ __launch_bounds__(256) void k_step_final(const float2* __restrict__ in,
                                                    const float2* __restrict__ ig,
                                                    float* __restrict__ trans,
                                                    float* __restrict__ disp) {
    int n, q;
    decode_block(blockIdx.x, n, q);

    const float2* img  = in + (size_t)n * HW;
    const float4* img4 = (const float4*)img;
    const float4* ig4  = (const float4*)ig;
    float4 d = img4[q];
    float4 g = nt_load4(&ig4[q]);  // (x0,y0,x1,y1) of pixels p, p+1

    float2 s0 = bilin_sample(img, g.x + d.x, g.y + d.y);
    float2 s1 = bilin_sample(img, g.z + d.z, g.w + d.w);

    float dx0 = d.x + s0.x, dy0 = d.y + s0.y;   // disp32 pixel p
    float dx1 = d.z + s1.x, dy1 = d.w + s1.y;   // disp32 pixel p+1

    int p = q * 2;
    float* dispn  = disp  + (size_t)n * PLANE;
    float* transn = trans + (size_t)n * PLANE;
    nt_store2(make_float2(dx0, dx1),             (float2*)(dispn + p));
    nt_store2(make_float2(dy0, dy1),             (float2*)(dispn + HW + p));
    nt_store2(make_float2(dx0 + g.x, dx1 + g.z), (float2*)(transn + p));
    nt_store2(make_float2(dy0 + g.y, dy1 + g.w), (float2*)(transn + HW + p));
}

// F1 (fallback): interleaved [N,H,W,2] -> planar displacement [N,2,H,W]
__global__ __launch_bounds__(256) void k_deinterleave(const float2* __restrict__ in,
                                                      float* __restrict__ disp) {
    int i = blockIdx.x * blockDim.x + threadIdx.x;  // pixel-pair index
    if (i >= NHW / 2) return;
    int n = i / (HW / 2);
    int qp = i - n * (HW / 2);
    int p = qp * 2;
    const float4* in4 = (const float4*)(in + (size_t)n * HW);
    float4 d = in4[qp];
    float* dispn = disp + (size_t)n * PLANE;
    *(float2*)(dispn + p)      = make_float2(d.x, d.z);
    *(float2*)(dispn + HW + p) = make_float2(d.y, d.w);
}

// F2 (fallback): transformation[n,c,y,x] = identity[y,x,c] + disp[n,c,y,x]
__global__ __launch_bounds__(256) void k_trans(const float* __restrict__ disp,
                                               const float2* __restrict__ ig,
                                               float* __restrict__ trans) {
    int i = blockIdx.x * blockDim.x + threadIdx.x;  // pixel-pair index
    if (i >= NHW / 2) return;
    int n = i / (HW / 2);
    int qp = i - n * (HW / 2);
    int p = qp * 2;
    const float4* ig4 = (const float4*)ig;
    float4 g = ig4[qp];  // (x0,y0,x1,y1) of pixels p, p+1
    const float* dispn = disp + (size_t)n * PLANE;
    float* transn = trans + (size_t)n * PLANE;
    float2 dx = *(const float2*)(dispn + p);
    float2 dy = *(const float2*)(dispn + HW + p);
    *(float2*)(transn + p)      = make_float2(dx.x + g.x, dx.y + g.z);
    *(float2*)(transn + HW + p) = make_float2(dy.x + g.y, dy.y + g.w);
}

// Launch step I (1..count): odd steps read pa write pb, even read pb write pa.
template<int I>
static inline void launch_step(float2* pa, float2* pb, const float2* ig, hipStream_t s) {
    const float2* src = (I & 1) ? (const float2*)pa : (const float2*)pb;
    float2* dst       = (I & 1) ? pb : pa;
    k_step<I><<<GRID_STEP, 256, 0, s>>>(src, ig, dst);
}

template<int... Is>
static inline void launch_all(std::integer_sequence<int, Is...>,
                              float2* pa, float2* pb, const float2* ig, hipStream_t s) {
    (launch_step<Is + 1>(pa, pb, ig, s), ...);
}

extern "C" void kernel_launch(void* const* d_in, const int* in_sizes, int n_in,
                              void* d_out, int out_size, void* d_ws, size_t ws_size,
                              hipStream_t stream) {
    const float*  v  = (const float*)d_in[0];
    const float2* ig = (const float2*)d_in[1];
    float* out = (float*)d_out;

    float2* h0 = (float2*)out;           // transformation slot (ping)
    float2* h1 = (float2*)(out + HALF);  // displacement slot

    const int threads = 256;
    const int blocks  = (NHW + threads - 1) / threads;

    // disp0 -> h0
    k_init<<<blocks, threads, 0, stream>>>(v, h0);

    const size_t need_ws = (size_t)NHW * sizeof(float2);  // 104.9 MB
    if (ws_size >= need_ws) {
        // Steps 1..31 ping-pong h0 <-> ws; step 31 (odd) lands in ws.
        float2* wsbuf = (float2*)d_ws;
        launch_all(std::make_integer_sequence<int, 31>{}, h0, wsbuf, ig, stream);
        // Fused final step: ws -> trans (h0, planar) + disp (h1, planar).
        k_step_final<<<GRID_STEP, 256, 0, stream>>>(wsbuf, ig, out, out + HALF);
    } else {
        // Fallback: original 32-step ping-pong + 2-kernel epilogue.
        launch_all(std::make_integer_sequence<int, 32>{}, h0, h1, ig, stream);
        const int blocks2 = (NHW / 2 + threads - 1) / threads;
        k_deinterleave<<<blocks2, threads, 0, stream>>>(h0, out + HALF);
        k_trans<<<blocks2, threads, 0, stream>>>(out + HALF, ig, out);
    }
}

// Round 2
// 1995.941 us; speedup vs baseline: 1.3991x; 1.3991x over previous
//
#include <hip/hip_runtime.h>
#include <utility>

// Problem constants (from reference)
#define NB   32
#define CH   2
#define HH   640
#define WW   640
#define HW   (HH * WW)        // 409600 pixels per image
#define NHW  (NB * HW)        // 13107200 pixels total
#define PLANE (CH * HW)       // 819200 floats per image, planar
#define HALF (NB * PLANE)     // 26214400 floats per output tensor

#define BLK_PX       1024                  // pixels per block (256 thr x 4 px)
#define QUADS_PER_BLK (BLK_PX / 2)         // 512 float4 (pixel-pair) slots
#define BLKS_PER_IMG (HW / BLK_PX)         // 400
#define GRID_STEP    (NB * BLKS_PER_IMG)   // 12800

// K0: v [N,2,H,W] planar -> disp0 interleaved [N,H,W,2], scaled by 2^-32
__global__ void k_init(const float* __restrict__ v, float2* __restrict__ out) {
    int idx = blockIdx.x * blockDim.x + threadIdx.x;
    if (idx >= NHW) return;
    int n = idx / HW;
    int p = idx - n * HW;
    const float s = 2.3283064365386963e-10f;  // 2^-32, exact
    float dx = v[n * PLANE + p] * s;
    float dy = v[n * PLANE + HW + p] * s;
    out[idx] = make_float2(dx, dy);
}

// Bilinear sample with border clamp, align_corners=True. img interleaved [H,W,2].
__device__ __forceinline__ float2 bilin_sample(const float2* __restrict__ img,
                                               float gx, float gy) {
    float fx = (gx + 1.0f) * (0.5f * (float)(WW - 1));
    float fy = (gy + 1.0f) * (0.5f * (float)(HH - 1));
    fx = fminf(fmaxf(fx, 0.0f), (float)(WW - 1));
    fy = fminf(fmaxf(fy, 0.0f), (float)(HH - 1));
    float x0f = floorf(fx);
    float y0f = floorf(fy);
    int x0 = (int)x0f;
    int y0 = (int)y0f;
    int x1 = min(x0 + 1, WW - 1);
    int y1 = min(y0 + 1, HH - 1);
    float wx = fx - x0f;
    float wy = fy - y0f;
    float omwx = 1.0f - wx;
    float omwy = 1.0f - wy;
    float2 v00 = img[y0 * WW + x0];
    float2 v01 = img[y0 * WW + x1];
    float2 v10 = img[y1 * WW + x0];
    float2 v11 = img[y1 * WW + x1];
    float topx = v00.x * omwx + v01.x * wx;
    float topy = v00.y * omwx + v01.y * wx;
    float botx = v10.x * omwx + v11.x * wx;
    float boty = v10.y * omwx + v11.y * wx;
    return make_float2(topx * omwy + botx * wy, topy * omwy + boty * wy);
}

// Block -> (image, base quad) with image pinned to XCD (blockIdx%8 heuristic).
// Each thread owns quads q0 and q0+256 (two fully-coalesced float4 streams).
__device__ __forceinline__ void decode_block(int b, int& n, int& q0) {
    int xcd = b & 7;
    int slot = b >> 3;                   // 0..1599
    int img_round = slot / BLKS_PER_IMG; // 0..3
    int blk = slot - img_round * BLKS_PER_IMG;
    n = img_round * 8 + xcd;             // image -> fixed XCD
    q0 = blk * QUADS_PER_BLK + threadIdx.x;
}

// One squaring step, 4 px/thread (2 float4 pixel-pairs), fully cached accesses.
// 16 independent tap loads per thread -> deep MLP for the late, scattered steps.
// STEP is only a symbol tag so rocprof separates the 32 dispatches.
template<int STEP>
__global__ __launch_bounds__(256) void k_step(const float2* __restrict__ in,
                                              const float2* __restrict__ ig,
                                              float2* __restrict__ out) {
    int n, q0;
    decode_block(blockIdx.x, n, q0);
    int q1 = q0 + 256;

    const float2* img  = in + (size_t)n * HW;
    const float4* img4 = (const float4*)img;
    const float4* ig4  = (const float4*)ig;
    float4 d0 = img4[q0];
    float4 d1 = img4[q1];
    float4 g0 = ig4[q0];
    float4 g1 = ig4[q1];

    float2 s00 = bilin_sample(img, g0.x + d0.x, g0.y + d0.y);
    float2 s01 = bilin_sample(img, g0.z + d0.z, g0.w + d0.w);
    float2 s10 = bilin_sample(img, g1.x + d1.x, g1.y + d1.y);
    float2 s11 = bilin_sample(img, g1.z + d1.z, g1.w + d1.w);

    float4* out4 = (float4*)(out + (size_t)n * HW);
    out4[q0] = make_float4(d0.x + s00.x, d0.y + s00.y, d0.z + s01.x, d0.w + s01.y);
    out4[q1] = make_float4(d1.x + s10.x, d1.y + s10.y, d1.z + s11.x, d1.w + s11.y);
}

// Final squaring step fused with the epilogue: reads disp31 (interleaved, in ws),
// writes BOTH planar outputs: disp32 -> disp, ig+disp32 -> trans.
// Replaces k_step<32> + k_deinterleave + k_trans (630 MB) with 315 MB.
__global__ __launch_bounds__(256) void k_step_final(const float2* __restrict__ in,
                                                    const float2* __restrict__ ig,
                                                    float* __restrict__ trans,
                                                    float* __restrict__ disp) {
    int n, q0;
    decode_block(blockIdx.x, n, q0);
    int q1 = q0 + 256;

    const float2* img  = in + (size_t)n * HW;
    const float4* img4 = (const float4*)img;
    const float4* ig4  = (const float4*)ig;
    float* dispn  = disp  + (size_t)n * PLANE;
    float* transn = trans + (size_t)n * PLANE;

    #pragma unroll
    for (int k = 0; k < 2; ++k) {
        int q = k ? q1 : q0;
        float4 d = img4[q];
        float4 g = ig4[q];  // (x0,y0,x1,y1) of pixels p, p+1
        float2 s0 = bilin_sample(img, g.x + d.x, g.y + d.y);
        float2 s1 = bilin_sample(img, g.z + d.z, g.w + d.w);
        float dx0 = d.x + s0.x, dy0 = d.y + s0.y;   // disp32 pixel p
        float dx1 = d.z + s1.x, dy1 = d.w + s1.y;   // disp32 pixel p+1
        int p = q * 2;
        *(float2*)(dispn + p)       = make_float2(dx0, dx1);
        *(float2*)(dispn + HW + p)  = make_float2(dy0, dy1);
        *(float2*)(transn + p)      = make_float2(dx0 + g.x, dx1 + g.z);
        *(float2*)(transn + HW + p) = make_float2(dy0 + g.y, dy1 + g.w);
    }
}

// F1 (fallback): interleaved [N,H,W,2] -> planar displacement [N,2,H,W]
__global__ __launch_bounds__(256) void k_deinterleave(const float2* __restrict__ in,
                                                      float* __restrict__ disp) {
    int i = blockIdx.x * blockDim.x + threadIdx.x;  // pixel-pair index
    if (i >= NHW / 2) return;
    int n = i / (HW / 2);
    int qp = i - n * (HW / 2);
    int p = qp * 2;
    const float4* in4 = (const float4*)(in + (size_t)n * HW);
    float4 d = in4[qp];
    float* dispn = disp + (size_t)n * PLANE;
    *(float2*)(dispn + p)      = make_float2(d.x, d.z);
    *(float2*)(dispn + HW + p) = make_float2(d.y, d.w);
}

// F2 (fallback): transformation[n,c,y,x] = identity[y,x,c] + disp[n,c,y,x]
__global__ __launch_bounds__(256) void k_trans(const float* __restrict__ disp,
                                               const float2* __restrict__ ig,
                                               float* __restrict__ trans) {
    int i = blockIdx.x * blockDim.x + threadIdx.x;  // pixel-pair index
    if (i >= NHW / 2) return;
    int n = i / (HW / 2);
    int qp = i - n * (HW / 2);
    int p = qp * 2;
    const float4* ig4 = (const float4*)ig;
    float4 g = ig4[qp];  // (x0,y0,x1,y1) of pixels p, p+1
    const float* dispn = disp + (size_t)n * PLANE;
    float* transn = trans + (size_t)n * PLANE;
    float2 dx = *(const float2*)(dispn + p);
    float2 dy = *(const float2*)(dispn + HW + p);
    *(float2*)(transn + p)      = make_float2(dx.x + g.x, dx.y + g.z);
    *(float2*)(transn + HW + p) = make_float2(dy.x + g.y, dy.y + g.w);
}

// Launch step I (1..count): odd steps read pa write pb, even read pb write pa.
template<int I>
static inline void launch_step(float2* pa, float2* pb, const float2* ig, hipStream_t s) {
    const float2* src = (I & 1) ? (const float2*)pa : (const float2*)pb;
    float2* dst       = (I & 1) ? pb : pa;
    k_step<I><<<GRID_STEP, 256, 0, s>>>(src, ig, dst);
}

template<int... Is>
static inline void launch_all(std::integer_sequence<int, Is...>,
                              float2* pa, float2* pb, const float2* ig, hipStream_t s) {
    (launch_step<Is + 1>(pa, pb, ig, s), ...);
}

extern "C" void kernel_launch(void* const* d_in, const int* in_sizes, int n_in,
                              void* d_out, int out_size, void* d_ws, size_t ws_size,
                              hipStream_t stream) {
    const float*  v  = (const float*)d_in[0];
    const float2* ig = (const float2*)d_in[1];
    float* out = (float*)d_out;

    float2* h0 = (float2*)out;           // transformation slot (ping)
    float2* h1 = (float2*)(out + HALF);  // displacement slot

    const int threads = 256;
    const int blocks  = (NHW + threads - 1) / threads;

    // disp0 -> h0
    k_init<<<blocks, threads, 0, stream>>>(v, h0);

    const size_t need_ws = (size_t)NHW * sizeof(float2);  // 104.9 MB
    if (ws_size >= need_ws) {
        // Steps 1..31 ping-pong h0 <-> ws; step 31 (odd) lands in ws.
        float2* wsbuf = (float2*)d_ws;
        launch_all(std::make_integer_sequence<int, 31>{}, h0, wsbuf, ig, stream);
        // Fused final step: ws -> trans (h0, planar) + disp (h1, planar).
        k_step_final<<<GRID_STEP, 256, 0, stream>>>(wsbuf, ig, out, out + HALF);
    } else {
        // Fallback: original 32-step ping-pong + 2-kernel epilogue.
        launch_all(std::make_integer_sequence<int, 32>{}, h0, h1, ig, stream);
        const int blocks2 = (NHW / 2 + threads - 1) / threads;
        k_deinterleave<<<blocks2, threads, 0, stream>>>(h0, out + HALF);
        k_trans<<<blocks2, threads, 0, stream>>>(out + HALF, ig, out);
    }
}

// Round 4
// 1727.555 us; speedup vs baseline: 1.6164x; 1.1554x over previous
//
#include <hip/hip_runtime.h>
#include <utility>

// Problem constants (from reference)
#define NB   32
#define CH   2
#define HH   640
#define WW   640
#define HW   (HH * WW)        // 409600 pixels per image
#define NHW  (NB * HW)        // 13107200 pixels total
#define PLANE (CH * HW)       // 819200 floats per image, planar
#define HALF (NB * PLANE)     // 26214400 floats per output tensor

#define BLK_PX       512                   // pixels per block (256 thr x 2 px)
#define QPB          (BLK_PX / 2)          // 256 float4 (pixel-pair) slots/block
#define BLKS_PER_IMG (HW / BLK_PX)         // 800
#define GRID_STEP    (NB * BLKS_PER_IMG)   // 25600

// 8B-aligned 4-float vector (row-pair load may sit at odd-pixel offsets).
struct alignas(8) f4u { float x, y, z, w; };
// 4B-aligned 2-float vector (planar row-pair load).
struct alignas(4) f2u { float x, y; };

// Block -> (image, pixel-quad) with image pinned to XCD (blockIdx%8 heuristic).
__device__ __forceinline__ void decode_block(int b, int& n, int& q) {
    int xcd = b & 7;
    int slot = b >> 3;                   // 0..3199
    int img_round = slot / BLKS_PER_IMG; // 0..3
    int blk = slot - img_round * BLKS_PER_IMG;
    n = img_round * 8 + xcd;             // image -> fixed XCD
    q = blk * QPB + threadIdx.x;         // float4 (pixel-pair) index in image
}

// Bilinear sample, border clamp, align_corners=True, reference-order coords:
// fx = ((gx) + 1) * (0.5*(W-1)).  Row-pair loads: v00,v01 are 16 contiguous
// bytes -> one 8B-aligned dwordx4 instead of two 8B loads (halves gather
// transactions).  Edge x0=W-1 handled by base shift: t = fx - xb hits 1.0,
// lerp(v638,v639,1) == v639 bitwise.
__device__ __forceinline__ float2 bilin_pair(const float2* __restrict__ img,
                                             float gx, float gy) {
    float fx = (gx + 1.0f) * (0.5f * (float)(WW - 1));
    float fy = (gy + 1.0f) * (0.5f * (float)(HH - 1));
    fx = fminf(fmaxf(fx, 0.0f), (float)(WW - 1));
    fy = fminf(fmaxf(fy, 0.0f), (float)(HH - 1));
    float x0f = floorf(fx);
    float y0f = floorf(fy);
    int x0 = (int)x0f;
    int y0 = (int)y0f;
    int y1 = min(y0 + 1, HH - 1);
    int xb = min(x0, WW - 2);
    float t    = fx - (float)xb;     // == wx interior; == 1.0 at right edge
    float omt  = 1.0f - t;
    float wy   = fy - y0f;
    float omwy = 1.0f - wy;
    const f4u* r0 = (const f4u*)(img + y0 * WW + xb);
    const f4u* r1 = (const f4u*)(img + y1 * WW + xb);
    f4u a = *r0;   // v00.x v00.y v01.x v01.y
    f4u b = *r1;   // v10.x v10.y v11.x v11.y
    float topx = a.x * omt + a.z * t;
    float topy = a.y * omt + a.w * t;
    float botx = b.x * omt + b.z * t;
    float boty = b.y * omt + b.w * t;
    return make_float2(topx * omwy + botx * wy, topy * omwy + boty * wy);
}

// Planar-source variant for step 1: samples v (unscaled) and multiplies by
// s = 2^-32 after the lerp (power-of-2 scale commutes bitwise with the lerp).
__device__ __forceinline__ float2 bilin_planar_pair(const float* __restrict__ vx,
                                                    const float* __restrict__ vy,
                                                    float gx, float gy, float s) {
    float fx = (gx + 1.0f) * (0.5f * (float)(WW - 1));
    float fy = (gy + 1.0f) * (0.5f * (float)(HH - 1));
    fx = fminf(fmaxf(fx, 0.0f), (float)(WW - 1));
    fy = fminf(fmaxf(fy, 0.0f), (float)(HH - 1));
    float x0f = floorf(fx);
    float y0f = floorf(fy);
    int x0 = (int)x0f;
    int y0 = (int)y0f;
    int y1 = min(y0 + 1, HH - 1);
    int xb = min(x0, WW - 2);
    float t    = fx - (float)xb;
    float omt  = 1.0f - t;
    float wy   = fy - y0f;
    float omwy = 1.0f - wy;
    int r0 = y0 * WW + xb;
    int r1 = y1 * WW + xb;
    f2u ax0 = *(const f2u*)(vx + r0);
    f2u ax1 = *(const f2u*)(vx + r1);
    f2u ay0 = *(const f2u*)(vy + r0);
    f2u ay1 = *(const f2u*)(vy + r1);
    float topx = ax0.x * omt + ax0.y * t;
    float topy = ay0.x * omt + ay0.y * t;
    float botx = ax1.x * omt + ax1.y * t;
    float boty = ay1.x * omt + ay1.y * t;
    return make_float2((topx * omwy + botx * wy) * s,
                       (topy * omwy + boty * wy) * s);
}

// Fused k_init + step 1: v [N,2,H,W] planar -> disp1 interleaved [N,H,W,2].
// disp0 = v * 2^-32 applied on the fly (exact); coords use the REAL ig in
// reference order: fx = ((g + d0) + 1) * 319.5.
__global__ __launch_bounds__(256) void k_init_step1(const float* __restrict__ v,
                                                    const float2* __restrict__ ig,
                                                    float2* __restrict__ out) {
    int n, q;
    decode_block(blockIdx.x, n, q);
    const float* vx = v + (size_t)n * PLANE;
    const float* vy = vx + HW;
    int p = q * 2;               // even -> float2 loads are 8B-aligned
    const float s = 2.3283064365386963e-10f;  // 2^-32, exact
    float2 dvx = *(const float2*)(vx + p);    // v_x at pixels p, p+1
    float2 dvy = *(const float2*)(vy + p);    // v_y at pixels p, p+1
    const float4* ig4 = (const float4*)ig;
    float4 g = ig4[q];           // (x0,y0,x1,y1) normalized, pixels p, p+1
    float dx0 = dvx.x * s, dy0 = dvy.x * s;
    float dx1 = dvx.y * s, dy1 = dvy.y * s;

    float2 s0 = bilin_planar_pair(vx, vy, g.x + dx0, g.y + dy0, s);
    float2 s1 = bilin_planar_pair(vx, vy, g.z + dx1, g.w + dy1, s);

    float4* out4 = (float4*)(out + (size_t)n * HW);
    out4[q] = make_float4(dx0 + s0.x, dy0 + s0.y, dx1 + s1.x, dy1 + s1.y);
}

// One squaring step, 2 px/thread, real ig, reference-order coords, pair loads.
// STEP is only a symbol tag so rocprof separates the dispatches.
template<int STEP>
__global__ __launch_bounds__(256) void k_step(const float2* __restrict__ in,
                                              const float2* __restrict__ ig,
                                              float2* __restrict__ out) {
    int n, q;
    decode_block(blockIdx.x, n, q);
    const float2* img  = in + (size_t)n * HW;
    const float4* img4 = (const float4*)img;
    const float4* ig4  = (const float4*)ig;
    float4 d = img4[q];
    float4 g = ig4[q];

    float2 s0 = bilin_pair(img, g.x + d.x, g.y + d.y);
    float2 s1 = bilin_pair(img, g.z + d.z, g.w + d.w);

    float4* out4 = (float4*)(out + (size_t)n * HW);
    out4[q] = make_float4(d.x + s0.x, d.y + s0.y, d.z + s1.x, d.w + s1.y);
}

// Final squaring step fused with the epilogue: reads disp31 (interleaved, ws),
// writes BOTH planar outputs: disp32 -> disp, ig+disp32 -> trans.
__global__ __launch_bounds__(256) void k_step_final(const float2* __restrict__ in,
                                                    const float2* __restrict__ ig,
                                                    float* __restrict__ trans,
                                                    float* __restrict__ disp) {
    int n, q;
    decode_block(blockIdx.x, n, q);
    const float2* img  = in + (size_t)n * HW;
    const float4* img4 = (const float4*)img;
    const float4* ig4  = (const float4*)ig;
    float4 d = img4[q];
    float4 g = ig4[q];  // (x0,y0,x1,y1) of pixels p, p+1

    float2 s0 = bilin_pair(img, g.x + d.x, g.y + d.y);
    float2 s1 = bilin_pair(img, g.z + d.z, g.w + d.w);

    float dx0 = d.x + s0.x, dy0 = d.y + s0.y;   // disp32 pixel p
    float dx1 = d.z + s1.x, dy1 = d.w + s1.y;   // disp32 pixel p+1

    int p = q * 2;
    float* dispn  = disp  + (size_t)n * PLANE;
    float* transn = trans + (size_t)n * PLANE;
    *(float2*)(dispn + p)       = make_float2(dx0, dx1);
    *(float2*)(dispn + HW + p)  = make_float2(dy0, dy1);
    *(float2*)(transn + p)      = make_float2(dx0 + g.x, dx1 + g.z);
    *(float2*)(transn + HW + p) = make_float2(dy0 + g.y, dy1 + g.w);
}

// ---------- fallback-path kernels (ws too small) ----------

__global__ void k_init(const float* __restrict__ v, float2* __restrict__ out) {
    int idx = blockIdx.x * blockDim.x + threadIdx.x;
    if (idx >= NHW) return;
    int n = idx / HW;
    int p = idx - n * HW;
    const float s = 2.3283064365386963e-10f;  // 2^-32, exact
    float dx = v[n * PLANE + p] * s;
    float dy = v[n * PLANE + HW + p] * s;
    out[idx] = make_float2(dx, dy);
}

__global__ __launch_bounds__(256) void k_deinterleave(const float2* __restrict__ in,
                                                      float* __restrict__ disp) {
    int i = blockIdx.x * blockDim.x + threadIdx.x;  // pixel-pair index
    if (i >= NHW / 2) return;
    int n = i / (HW / 2);
    int qp = i - n * (HW / 2);
    int p = qp * 2;
    const float4* in4 = (const float4*)(in + (size_t)n * HW);
    float4 d = in4[qp];
    float* dispn = disp + (size_t)n * PLANE;
    *(float2*)(dispn + p)      = make_float2(d.x, d.z);
    *(float2*)(dispn + HW + p) = make_float2(d.y, d.w);
}

__global__ __launch_bounds__(256) void k_trans(const float* __restrict__ disp,
                                               const float2* __restrict__ ig,
                                               float* __restrict__ trans) {
    int i = blockIdx.x * blockDim.x + threadIdx.x;  // pixel-pair index
    if (i >= NHW / 2) return;
    int n = i / (HW / 2);
    int qp = i - n * (HW / 2);
    int p = qp * 2;
    const float4* ig4 = (const float4*)ig;
    float4 g = ig4[qp];  // (x0,y0,x1,y1) of pixels p, p+1
    const float* dispn = disp + (size_t)n * PLANE;
    float* transn = trans + (size_t)n * PLANE;
    float2 dx = *(const float2*)(dispn + p);
    float2 dy = *(const float2*)(dispn + HW + p);
    *(float2*)(transn + p)      = make_float2(dx.x + g.x, dx.y + g.z);
    *(float2*)(transn + HW + p) = make_float2(dy.x + g.y, dy.y + g.w);
}

// ---------- launch helpers ----------

// Middle steps I=2..31 (ws path): disp1 starts in ws; odd I read h0 -> ws,
// even I read ws -> h0.  disp31 (I=31, odd) ends in ws.
template<int I>
static inline void launch_mid(float2* h0, float2* ws, const float2* ig, hipStream_t s) {
    const float2* src = (I & 1) ? (const float2*)h0 : (const float2*)ws;
    float2* dst       = (I & 1) ? ws : h0;
    k_step<I><<<GRID_STEP, 256, 0, s>>>(src, ig, dst);
}

template<int... Is>
static inline void launch_mids(std::integer_sequence<int, Is...>,
                               float2* h0, float2* ws, const float2* ig, hipStream_t s) {
    (launch_mid<Is + 2>(h0, ws, ig, s), ...);
}

// Fallback steps I=1..32: odd read h0 -> h1, even read h1 -> h0.
template<int I>
static inline void launch_fb(float2* h0, float2* h1, const float2* ig, hipStream_t s) {
    const float2* src = (I & 1) ? (const float2*)h0 : (const float2*)h1;
    float2* dst       = (I & 1) ? h1 : h0;
    k_step<I><<<GRID_STEP, 256, 0, s>>>(src, ig, dst);
}

template<int... Is>
static inline void launch_fbs(std::integer_sequence<int, Is...>,
                              float2* h0, float2* h1, const float2* ig, hipStream_t s) {
    (launch_fb<Is + 1>(h0, h1, ig, s), ...);
}

extern "C" void kernel_launch(void* const* d_in, const int* in_sizes, int n_in,
                              void* d_out, int out_size, void* d_ws, size_t ws_size,
                              hipStream_t stream) {
    const float*  v  = (const float*)d_in[0];
    const float2* ig = (const float2*)d_in[1];
    float* out = (float*)d_out;

    float2* h0 = (float2*)out;           // transformation slot
    float2* h1 = (float2*)(out + HALF);  // displacement slot

    const size_t need_ws = (size_t)NHW * sizeof(float2);  // 104.9 MB
    if (ws_size >= need_ws) {
        float2* wsbuf = (float2*)d_ws;
        // Fused init + step 1: v -> disp1 in ws.
        k_init_step1<<<GRID_STEP, 256, 0, stream>>>(v, ig, wsbuf);
        // Steps 2..31 ping-pong ws <-> h0; disp31 lands in ws.
        launch_mids(std::make_integer_sequence<int, 30>{}, h0, wsbuf, ig, stream);
        // Fused final step: ws -> trans (out, planar) + disp (out+HALF, planar).
        k_step_final<<<GRID_STEP, 256, 0, stream>>>(wsbuf, ig, out, out + HALF);
    } else {
        // Fallback: original structure (no workspace).
        const int threads = 256;
        const int blocks  = (NHW + threads - 1) / threads;
        k_init<<<blocks, threads, 0, stream>>>(v, h0);
        launch_fbs(std::make_integer_sequence<int, 32>{}, h0, h1, ig, stream);
        const int blocks2 = (NHW / 2 + threads - 1) / threads;
        k_deinterleave<<<blocks2, threads, 0, stream>>>(h0, out + HALF);
        k_trans<<<blocks2, threads, 0, stream>>>(out + HALF, ig, out);
    }
}

// Round 6
// 1391.604 us; speedup vs baseline: 2.0067x; 1.2414x over previous
//
#include <hip/hip_runtime.h>
#include <utility>

// Problem constants (from reference)
#define NB   32
#define CH   2
#define HH   640
#define WW   640
#define HW   (HH * WW)        // 409600 pixels per image
#define NHW  (NB * HW)        // 13107200 pixels total
#define PLANE (CH * HW)       // 819200 floats per image, planar
#define HALF (NB * PLANE)     // 26214400 floats per output tensor

#define BLK_PX       512                   // pixels per block (256 thr x 2 px)
#define QPB          (BLK_PX / 2)          // 256 float4 (pixel-pair) slots/block
#define BLKS_PER_IMG (HW / BLK_PX)         // 800
#define GRID_STEP    (NB * BLKS_PER_IMG)   // 25600

// 8B-aligned 4-float vector (row-pair load may sit at odd-pixel offsets).
struct alignas(8) f4u { float x, y, z, w; };
// 8B-aligned 2-float vector.
struct alignas(8) f2a { float x, y; };
// 4B-aligned 2-float vector (planar row-pair load).
struct alignas(4) f2u { float x, y; };

// Separable identity-grid tables: ig[y][x] == (g_xs[x], g_ys[y]) bit-exact.
// 5 KB total -> stays L1-resident on every CU; removes the 3.28 MB ig stream
// from L2 so the gather image has the whole 4 MB per-XCD L2 to itself.
__device__ float g_xs[WW];
__device__ float g_ys[HH];

// Extract the tables from the real ig tensor (bit-identical values; we never
// RECOMPUTE coordinates -- round-3 failure showed the map amplifies any ulp).
__global__ void k_extract(const float2* __restrict__ ig) {
    int i = blockIdx.x * blockDim.x + threadIdx.x;
    if (i < WW) g_xs[i] = ig[i].x;          // row 0: x varies, .x = xs[i]
    if (i < HH) g_ys[i] = ig[i * WW].y;     // col 0: y varies, .y = ys[i]
}

// Block -> (image, pixel-quad) with image pinned to XCD (blockIdx%8 heuristic).
__device__ __forceinline__ void decode_block(int b, int& n, int& q) {
    int xcd = b & 7;
    int slot = b >> 3;                   // 0..3199
    int img_round = slot / BLKS_PER_IMG; // 0..3
    int blk = slot - img_round * BLKS_PER_IMG;
    n = img_round * 8 + xcd;             // image -> fixed XCD
    q = blk * QPB + threadIdx.x;         // float4 (pixel-pair) index in image
}

// Bilinear sample, border clamp, align_corners=True, reference-order coords:
// fx = ((gx) + 1) * (0.5*(W-1)).  Row-pair loads: v00,v01 are 16 contiguous
// bytes -> one 8B-aligned dwordx4 instead of two 8B loads (halves gather
// transactions).  Edge x0=W-1 handled by base shift: t = fx - xb hits 1.0,
// lerp(v638,v639,1) == v639 bitwise.
__device__ __forceinline__ float2 bilin_pair(const float2* __restrict__ img,
                                             float gx, float gy) {
    float fx = (gx + 1.0f) * (0.5f * (float)(WW - 1));
    float fy = (gy + 1.0f) * (0.5f * (float)(HH - 1));
    fx = fminf(fmaxf(fx, 0.0f), (float)(WW - 1));
    fy = fminf(fmaxf(fy, 0.0f), (float)(HH - 1));
    float x0f = floorf(fx);
    float y0f = floorf(fy);
    int x0 = (int)x0f;
    int y0 = (int)y0f;
    int y1 = min(y0 + 1, HH - 1);
    int xb = min(x0, WW - 2);
    float t    = fx - (float)xb;     // == wx interior; == 1.0 at right edge
    float omt  = 1.0f - t;
    float wy   = fy - y0f;
    float omwy = 1.0f - wy;
    const f4u* r0 = (const f4u*)(img + y0 * WW + xb);
    const f4u* r1 = (const f4u*)(img + y1 * WW + xb);
    f4u a = *r0;   // v00.x v00.y v01.x v01.y
    f4u b = *r1;   // v10.x v10.y v11.x v11.y
    float topx = a.x * omt + a.z * t;
    float topy = a.y * omt + a.w * t;
    float botx = b.x * omt + b.z * t;
    float boty = b.y * omt + b.w * t;
    return make_float2(topx * omwy + botx * wy, topy * omwy + boty * wy);
}

// Planar-source variant for step 1: samples v (unscaled) and multiplies by
// s = 2^-32 after the lerp (power-of-2 scale commutes bitwise with the lerp).
__device__ __forceinline__ float2 bilin_planar_pair(const float* __restrict__ vx,
                                                    const float* __restrict__ vy,
                                                    float gx, float gy, float s) {
    float fx = (gx + 1.0f) * (0.5f * (float)(WW - 1));
    float fy = (gy + 1.0f) * (0.5f * (float)(HH - 1));
    fx = fminf(fmaxf(fx, 0.0f), (float)(WW - 1));
    fy = fminf(fmaxf(fy, 0.0f), (float)(HH - 1));
    float x0f = floorf(fx);
    float y0f = floorf(fy);
    int x0 = (int)x0f;
    int y0 = (int)y0f;
    int y1 = min(y0 + 1, HH - 1);
    int xb = min(x0, WW - 2);
    float t    = fx - (float)xb;
    float omt  = 1.0f - t;
    float wy   = fy - y0f;
    float omwy = 1.0f - wy;
    int r0 = y0 * WW + xb;
    int r1 = y1 * WW + xb;
    f2u ax0 = *(const f2u*)(vx + r0);
    f2u ax1 = *(const f2u*)(vx + r1);
    f2u ay0 = *(const f2u*)(vy + r0);
    f2u ay1 = *(const f2u*)(vy + r1);
    float topx = ax0.x * omt + ax0.y * t;
    float topy = ay0.x * omt + ay0.y * t;
    float botx = ax1.x * omt + ax1.y * t;
    float boty = ay1.x * omt + ay1.y * t;
    return make_float2((topx * omwy + botx * wy) * s,
                       (topy * omwy + boty * wy) * s);
}

// Per-thread identity-grid values from the L1-resident tables.
// Pixel pair p,p+1 never straddles a row (p even, WW even).
__device__ __forceinline__ void grid_pair(int p, float& gx0, float& gx1, float& gy) {
    int y = p / WW;
    int x = p - y * WW;
    f2a gx2 = *(const f2a*)(g_xs + x);   // x even -> 8B aligned
    gx0 = gx2.x;
    gx1 = gx2.y;
    gy  = g_ys[y];
}

// Fused k_init + step 1: v [N,2,H,W] planar -> disp1 interleaved [N,H,W,2].
// disp0 = v * 2^-32 applied on the fly (exact).
__global__ __launch_bounds__(256) void k_init_step1(const float* __restrict__ v,
                                                    float2* __restrict__ out) {
    int n, q;
    decode_block(blockIdx.x, n, q);
    const float* vx = v + (size_t)n * PLANE;
    const float* vy = vx + HW;
    int p = q * 2;               // even -> float2 loads are 8B-aligned
    const float s = 2.3283064365386963e-10f;  // 2^-32, exact
    float2 dvx = *(const float2*)(vx + p);    // v_x at pixels p, p+1
    float2 dvy = *(const float2*)(vy + p);    // v_y at pixels p, p+1
    float gx0, gx1, gy;
    grid_pair(p, gx0, gx1, gy);
    float dx0 = dvx.x * s, dy0 = dvy.x * s;
    float dx1 = dvx.y * s, dy1 = dvy.y * s;

    float2 s0 = bilin_planar_pair(vx, vy, gx0 + dx0, gy + dy0, s);
    float2 s1 = bilin_planar_pair(vx, vy, gx1 + dx1, gy + dy1, s);

    float4* out4 = (float4*)(out + (size_t)n * HW);
    out4[q] = make_float4(dx0 + s0.x, dy0 + s0.y, dx1 + s1.x, dy1 + s1.y);
}

// One squaring step, 2 px/thread; identity grid from L1 tables (bit-exact),
// so the ONLY L2-cached stream is the gather image itself (3.28 MB < 4 MB).
// STEP is only a symbol tag so rocprof separates the dispatches.
template<int STEP>
__global__ __launch_bounds__(256) void k_step(const float2* __restrict__ in,
                                              float2* __restrict__ out) {
    int n, q;
    decode_block(blockIdx.x, n, q);
    const float2* img  = in + (size_t)n * HW;
    const float4* img4 = (const float4*)img;
    float4 d = img4[q];
    float gx0, gx1, gy;
    grid_pair(q * 2, gx0, gx1, gy);

    float2 s0 = bilin_pair(img, gx0 + d.x, gy + d.y);
    float2 s1 = bilin_pair(img, gx1 + d.z, gy + d.w);

    float4* out4 = (float4*)(out + (size_t)n * HW);
    out4[q] = make_float4(d.x + s0.x, d.y + s0.y, d.z + s1.x, d.w + s1.y);
}

// Final squaring step fused with the epilogue: reads disp31 (interleaved, ws),
// writes BOTH planar outputs: disp32 -> disp, ig+disp32 -> trans.
__global__ __launch_bounds__(256) void k_step_final(const float2* __restrict__ in,
                                                    float* __restrict__ trans,
                                                    float* __restrict__ disp) {
    int n, q;
    decode_block(blockIdx.x, n, q);
    const float2* img  = in + (size_t)n * HW;
    const float4* img4 = (const float4*)img;
    float4 d = img4[q];
    int p = q * 2;
    float gx0, gx1, gy;
    grid_pair(p, gx0, gx1, gy);

    float2 s0 = bilin_pair(img, gx0 + d.x, gy + d.y);
    float2 s1 = bilin_pair(img, gx1 + d.z, gy + d.w);

    float dx0 = d.x + s0.x, dy0 = d.y + s0.y;   // disp32 pixel p
    float dx1 = d.z + s1.x, dy1 = d.w + s1.y;   // disp32 pixel p+1

    float* dispn  = disp  + (size_t)n * PLANE;
    float* transn = trans + (size_t)n * PLANE;
    *(float2*)(dispn + p)       = make_float2(dx0, dx1);
    *(float2*)(dispn + HW + p)  = make_float2(dy0, dy1);
    *(float2*)(transn + p)      = make_float2(dx0 + gx0, dx1 + gx1);
    *(float2*)(transn + HW + p) = make_float2(dy0 + gy,  dy1 + gy);
}

// ---------- fallback-path kernels (ws too small) ----------

__global__ void k_init(const float* __restrict__ v, float2* __restrict__ out) {
    int idx = blockIdx.x * blockDim.x + threadIdx.x;
    if (idx >= NHW) return;
    int n = idx / HW;
    int p = idx - n * HW;
    const float s = 2.3283064365386963e-10f;  // 2^-32, exact
    float dx = v[n * PLANE + p] * s;
    float dy = v[n * PLANE + HW + p] * s;
    out[idx] = make_float2(dx, dy);
}

__global__ __launch_bounds__(256) void k_deinterleave(const float2* __restrict__ in,
                                                      float* __restrict__ disp) {
    int i = blockIdx.x * blockDim.x + threadIdx.x;  // pixel-pair index
    if (i >= NHW / 2) return;
    int n = i / (HW / 2);
    int qp = i - n * (HW / 2);
    int p = qp * 2;
    const float4* in4 = (const float4*)(in + (size_t)n * HW);
    float4 d = in4[qp];
    float* dispn = disp + (size_t)n * PLANE;
    *(float2*)(dispn + p)      = make_float2(d.x, d.z);
    *(float2*)(dispn + HW + p) = make_float2(d.y, d.w);
}

__global__ __launch_bounds__(256) void k_trans(const float* __restrict__ disp,
                                               const float2* __restrict__ ig,
                                               float* __restrict__ trans) {
    int i = blockIdx.x * blockDim.x + threadIdx.x;  // pixel-pair index
    if (i >= NHW / 2) return;
    int n = i / (HW / 2);
    int qp = i - n * (HW / 2);
    int p = qp * 2;
    const float4* ig4 = (const float4*)ig;
    float4 g = ig4[qp];  // (x0,y0,x1,y1) of pixels p, p+1
    const float* dispn = disp + (size_t)n * PLANE;
    float* transn = trans + (size_t)n * PLANE;
    float2 dx = *(const float2*)(dispn + p);
    float2 dy = *(const float2*)(dispn + HW + p);
    *(float2*)(transn + p)      = make_float2(dx.x + g.x, dx.y + g.z);
    *(float2*)(transn + HW + p) = make_float2(dy.x + g.y, dy.y + g.w);
}

// ---------- launch helpers ----------

// Middle steps I=2..31 (ws path): disp1 starts in ws; odd I read h0 -> ws,
// even I read ws -> h0.  disp31 (I=31, odd) ends in ws.
template<int I>
static inline void launch_mid(float2* h0, float2* ws, hipStream_t s) {
    const float2* src = (I & 1) ? (const float2*)h0 : (const float2*)ws;
    float2* dst       = (I & 1) ? ws : h0;
    k_step<I><<<GRID_STEP, 256, 0, s>>>(src, dst);
}

template<int... Is>
static inline void launch_mids(std::integer_sequence<int, Is...>,
                               float2* h0, float2* ws, hipStream_t s) {
    (launch_mid<Is + 2>(h0, ws, s), ...);
}

// Fallback steps I=1..32: odd read h0 -> h1, even read h1 -> h0.
template<int I>
static inline void launch_fb(float2* h0, float2* h1, hipStream_t s) {
    const float2* src = (I & 1) ? (const float2*)h0 : (const float2*)h1;
    float2* dst       = (I & 1) ? h1 : h0;
    k_step<I><<<GRID_STEP, 256, 0, s>>>(src, dst);
}

template<int... Is>
static inline void launch_fbs(std::integer_sequence<int, Is...>,
                              float2* h0, float2* h1, hipStream_t s) {
    (launch_fb<Is + 1>(h0, h1, s), ...);
}

extern "C" void kernel_launch(void* const* d_in, const int* in_sizes, int n_in,
                              void* d_out, int out_size, void* d_ws, size_t ws_size,
                              hipStream_t stream) {
    const float*  v  = (const float*)d_in[0];
    const float2* ig = (const float2*)d_in[1];
    float* out = (float*)d_out;

    float2* h0 = (float2*)out;           // transformation slot
    float2* h1 = (float2*)(out + HALF);  // displacement slot

    // Extract the separable identity-grid tables (bit-exact ig values, 5 KB).
    k_extract<<<3, 256, 0, stream>>>(ig);

    const size_t need_ws = (size_t)NHW * sizeof(float2);  // 104.9 MB
    if (ws_size >= need_ws) {
        float2* wsbuf = (float2*)d_ws;
        // Fused init + step 1: v -> disp1 in ws.
        k_init_step1<<<GRID_STEP, 256, 0, stream>>>(v, wsbuf);
        // Steps 2..31 ping-pong ws <-> h0; disp31 lands in ws.
        launch_mids(std::make_integer_sequence<int, 30>{}, h0, wsbuf, stream);
        // Fused final step: ws -> trans (out, planar) + disp (out+HALF, planar).
        k_step_final<<<GRID_STEP, 256, 0, stream>>>(wsbuf, out, out + HALF);
    } else {
        // Fallback: original structure (no workspace).
        const int threads = 256;
        const int blocks  = (NHW + threads - 1) / threads;
        k_init<<<blocks, threads, 0, stream>>>(v, h0);
        launch_fbs(std::make_integer_sequence<int, 32>{}, h0, h1, stream);
        const int blocks2 = (NHW / 2 + threads - 1) / threads;
        k_deinterleave<<<blocks2, threads, 0, stream>>>(h0, out + HALF);
        k_trans<<<blocks2, threads, 0, stream>>>(out + HALF, ig, out);
    }
}